// Round 16
// baseline (1128.981 us; speedup 1.0000x reference)
//
#include <hip/hip_runtime.h>
#include <hip/hip_bf16.h>

#define NN 20000
#define NE 640000
#define DSH 9
#define NB 10
#define ATTR 4

typedef __attribute__((ext_vector_type(8))) short bfrag8;  // 8 bf16 (4 VGPR)
typedef __attribute__((ext_vector_type(4))) float f32x4;
typedef unsigned int u32;
typedef unsigned short u16;

constexpr float INV_SQRT_NB = 0.17677669529663687f; // 1/sqrt(32)

// silu via fast rcp (proven R8-R15): rel err 2^-22 << bf16 rounding
__device__ __forceinline__ float silu_f(float x) {
    return x * __builtin_amdgcn_rcpf(1.0f + __expf(-x));
}

__device__ __forceinline__ u16 f2bf(float v) {
    union { __hip_bfloat16 h; u16 u; } c;
    c.h = __float2bfloat16(v);
    return c.u;
}

__device__ __forceinline__ f32x4 mfma16(bfrag8 a, bfrag8 b, f32x4 c) {
    return __builtin_amdgcn_mfma_f32_16x16x32_bf16(a, b, c, 0, 0, 0);
}

// ---------------------------------------------------------------------------
// CSR builds (R14-exact). Fused dual-pass for the sorted tier; fill2 emits
// ordS[slot]=edge so the permute pass is slot-major with coalesced writes.
// ---------------------------------------------------------------------------
__global__ void count_k(const int* __restrict__ idx, int* __restrict__ cnt) {
    int i = blockIdx.x * blockDim.x + threadIdx.x;
    int st = gridDim.x * blockDim.x;
    for (; i < NE; i += st) atomicAdd(&cnt[idx[i]], 1);
}

__global__ void count2_k(const int* __restrict__ dst, const int* __restrict__ src,
                         int* __restrict__ cntD, int* __restrict__ cntS) {
    int i = blockIdx.x * blockDim.x + threadIdx.x;
    int st = gridDim.x * blockDim.x;
    for (; i < NE; i += st) {
        atomicAdd(&cntD[dst[i]], 1);
        atomicAdd(&cntS[src[i]], 1);
    }
}

__device__ __forceinline__ void scan_body(const int* __restrict__ cnt, int* __restrict__ ptr) {
    __shared__ int ssum[256];
    const int T = 256, t = threadIdx.x;
    const int strip = (NN + T - 1) / T;
    int base = t * strip, s = 0;
    for (int i = 0; i < strip; i++) { int idx = base + i; if (idx < NN) s += cnt[idx]; }
    ssum[t] = s; __syncthreads();
    for (int off = 1; off < T; off <<= 1) {
        int v = (t >= off) ? ssum[t - off] : 0;
        __syncthreads();
        ssum[t] += v;
        __syncthreads();
    }
    int run = (t == 0) ? 0 : ssum[t - 1];
    for (int i = 0; i < strip; i++) {
        int idx = base + i;
        if (idx < NN) { int c = cnt[idx]; ptr[idx] = run; run += c; }
    }
    if (t == T - 1) ptr[NN] = run;
}

__global__ void scan_k(const int* __restrict__ cnt, int* __restrict__ ptr) {
    scan_body(cnt, ptr);
}

__global__ void scan2_k(const int* __restrict__ cntD, int* __restrict__ ptrD,
                        const int* __restrict__ cntS, int* __restrict__ ptrS) {
    if (blockIdx.x == 0) scan_body(cntD, ptrD);
    else                 scan_body(cntS, ptrS);
}

__global__ void fill_k(const int* __restrict__ idx, const int* __restrict__ ptr,
                       int* __restrict__ cnt, int* __restrict__ pos) {
    int i = blockIdx.x * blockDim.x + threadIdx.x;
    int st = gridDim.x * blockDim.x;
    for (; i < NE; i += st) {
        int d = idx[i];
        int r = atomicAdd(&cnt[d], 1);
        pos[i] = ptr[d] + r;
    }
}

__global__ void fill2_k(const int* __restrict__ dst, const int* __restrict__ src,
                        const int* __restrict__ ptrD, const int* __restrict__ ptrS,
                        int* __restrict__ cntD, int* __restrict__ cntS,
                        int* __restrict__ pos, int* __restrict__ ordS) {
    int i = blockIdx.x * blockDim.x + threadIdx.x;
    int st = gridDim.x * blockDim.x;
    for (; i < NE; i += st) {
        int d = dst[i];
        pos[i] = ptrD[d] + atomicAdd(&cntD[d], 1);
        int s = src[i];
        ordS[ptrS[s] + atomicAdd(&cntS[s], 1)] = i;
    }
}

// ---------------------------------------------------------------------------
// Slot-major edge materialization (R14-exact): random 40B reads, coalesced
// writes of packed bf16 rows [E][20] (0..9 emb, 10..18 sh, 19 pad).
// ---------------------------------------------------------------------------
__global__ void permute_pack_g(const float* __restrict__ emb, const float* __restrict__ sh,
                               const int* __restrict__ src, const int* __restrict__ pos,
                               const int* __restrict__ ordS,
                               u16* __restrict__ embsh, int* __restrict__ srcS,
                               int* __restrict__ posD2)
{
    int s = blockIdx.x * blockDim.x + threadIdx.x;
    if (s >= NE) return;
    int e = ordS[s];
    u16* row = embsh + (size_t)s * 20;
    #pragma unroll
    for (int k = 0; k < NB; k++)  row[k]      = f2bf(emb[(size_t)e * NB + k]);
    #pragma unroll
    for (int k = 0; k < DSH; k++) row[NB + k] = f2bf(sh[(size_t)e * DSH + k]);
    row[19] = 0;
    srcS[s]  = src[e];
    posD2[s] = pos[e];
}

// ---------------------------------------------------------------------------
// Fused weight packing (R14-exact): all 12 tensors in one launch.
// ---------------------------------------------------------------------------
__global__ void pack_all(const float* __restrict__ W1_0, const float* __restrict__ W2_0,
                         const float* __restrict__ W3_0, const float* __restrict__ B0,
                         const float* __restrict__ W1_1, const float* __restrict__ W2_1,
                         const float* __restrict__ W3_1, const float* __restrict__ B1,
                         const float* __restrict__ W1_2, const float* __restrict__ W2_2,
                         const float* __restrict__ W3_2, const float* __restrict__ B2,
                         u16* __restrict__ w1f0, u16* __restrict__ w2f0,
                         u16* __restrict__ w3f0, u16* __restrict__ bf0,
                         u16* __restrict__ w1f1, u16* __restrict__ w2f1,
                         u16* __restrict__ w3f1, u16* __restrict__ bf1,
                         u16* __restrict__ w1f2, u16* __restrict__ w2f2,
                         u16* __restrict__ w3f2, u16* __restrict__ bf2)
{
    int tid = blockIdx.x * blockDim.x + threadIdx.x;
    int grp = tid >> 6, l = tid & 63;
    if (grp >= 155) return;
    const float* W; u16* out; int K, N, KS, local;
    if      (grp <   4) { W = W1_0; out = w1f0; K = 10;  N = 64;  KS = 1; local = grp;       }
    else if (grp <  20) { W = W2_0; out = w2f0; K = 64;  N = 128; KS = 2; local = grp - 4;   }
    else if (grp <  56) { W = W3_0; out = w3f0; K = 128; N = 144; KS = 4; local = grp - 20;  }
    else if (grp <  65) { W = B0;   out = bf0;  K = 9;   N = 144; KS = 1; local = grp - 56;  }
    else if (grp <  69) { W = W1_1; out = w1f1; K = 10;  N = 64;  KS = 1; local = grp - 65;  }
    else if (grp <  85) { W = W2_1; out = w2f1; K = 64;  N = 128; KS = 2; local = grp - 69;  }
    else if (grp < 121) { W = W3_1; out = w3f1; K = 128; N = 144; KS = 4; local = grp - 85;  }
    else if (grp < 130) { W = B1;   out = bf1;  K = 9;   N = 144; KS = 1; local = grp - 121; }
    else if (grp < 134) { W = W1_2; out = w1f2; K = 10;  N = 64;  KS = 1; local = grp - 130; }
    else if (grp < 150) { W = W2_2; out = w2f2; K = 64;  N = 128; KS = 2; local = grp - 134; }
    else if (grp < 154) { W = W3_2; out = w3f2; K = 128; N = 3;   KS = 4; local = grp - 150; }
    else                { W = B2;   out = bf2;  K = 9;   N = 3;   KS = 1; local = grp - 154; }
    int s = local % KS, t = local / KS;
    int kb = s * 32 + ((l >> 4) << 3);
    int n = t * 16 + (l & 15);
    #pragma unroll
    for (int j = 0; j < 8; j++) {
        int k = kb + j;
        float v = (k < K && n < N) ? W[(size_t)k * N + n] : 0.f;
        out[(size_t)(local * 64 + l) * 8 + j] = f2bf(v);
    }
}

// ---------------------------------------------------------------------------
// Per-node prep (layer 0 only): xa = x @ A, agg = outer(x, attr) @ Wsc
// ---------------------------------------------------------------------------
template<int DI, int DO, int NT>
__global__ void node_prep(const float* __restrict__ xin,
                          const float* __restrict__ attr,
                          const float* __restrict__ A,
                          const float* __restrict__ Wsc,
                          float* __restrict__ xa,
                          float* __restrict__ agg)
{
    __shared__ float sx[NT][DI];
    __shared__ float sat[NT][ATTR];
    const int n0 = blockIdx.x * NT;
    for (int idx = threadIdx.x; idx < NT * DI; idx += blockDim.x)
        sx[idx / DI][idx % DI] = xin[(size_t)n0 * DI + idx];
    if (threadIdx.x < NT * ATTR)
        sat[threadIdx.x / ATTR][threadIdx.x % ATTR] = attr[(size_t)n0 * ATTR + threadIdx.x];
    __syncthreads();

    const int o = threadIdx.x;
    if (o < DO) {
        float at[NT][ATTR];
        #pragma unroll
        for (int n = 0; n < NT; n++) {
            at[n][0] = sat[n][0]; at[n][1] = sat[n][1];
            at[n][2] = sat[n][2]; at[n][3] = sat[n][3];
        }
        float accA[NT], accS[NT];
        #pragma unroll
        for (int n = 0; n < NT; n++) { accA[n] = 0.f; accS[n] = 0.f; }
        for (int i = 0; i < DI; i++) {
            float a  = A[(size_t)i * DO + o];
            float w0 = Wsc[(size_t)(i * 4 + 0) * DO + o];
            float w1 = Wsc[(size_t)(i * 4 + 1) * DO + o];
            float w2 = Wsc[(size_t)(i * 4 + 2) * DO + o];
            float w3 = Wsc[(size_t)(i * 4 + 3) * DO + o];
            #pragma unroll
            for (int n = 0; n < NT; n++) {
                float xi = sx[n][i];
                accA[n] = fmaf(xi, a, accA[n]);
                float s = fmaf(at[n][3], w3,
                          fmaf(at[n][2], w2,
                          fmaf(at[n][1], w1, at[n][0] * w0)));
                accS[n] = fmaf(xi, s, accS[n]);
            }
        }
        #pragma unroll
        for (int n = 0; n < NT; n++) {
            xa [(size_t)(n0 + n) * DO + o] = accA[n];
            agg[(size_t)(n0 + n) * DO + o] = accS[n];
        }
    }
}

// ---------------------------------------------------------------------------
// FUSED layer boundary (R15-exact): gather + self-conn + silu -> LDS, then
// next-layer node_prep. No read/write aliasing.
// ---------------------------------------------------------------------------
template<int DOUT>
__global__ void __launch_bounds__(256)
gnp(const u32* __restrict__ msgdw, const int* __restrict__ ptr,
    const float* __restrict__ sc, const float* __restrict__ attr,
    const float* __restrict__ A, const float* __restrict__ Wsc,
    float* __restrict__ xa, float* __restrict__ aggo)
{
    __shared__ float sx[8][144];
    __shared__ float sat[8][ATTR];
    const int n0 = blockIdx.x * 8;
    const int wid = threadIdx.x >> 6, lane = threadIdx.x & 63;

    #pragma unroll
    for (int k = 0; k < 2; k++) {
        const int nl = wid * 2 + k;
        const int n = n0 + nl;
        const int s0 = ptr[n], s1 = ptr[n + 1];
        float a0 = 0.f, a1 = 0.f, b0 = 0.f, b1 = 0.f;
        for (int s = s0; s < s1; s++) {
            u32 u = msgdw[(size_t)s * 72 + lane];
            a0 += __uint_as_float(u << 16);
            a1 += __uint_as_float(u & 0xffff0000u);
            if (lane < 8) {
                u32 v = msgdw[(size_t)s * 72 + 64 + lane];
                b0 += __uint_as_float(v << 16);
                b1 += __uint_as_float(v & 0xffff0000u);
            }
        }
        size_t base = (size_t)n * 144;
        float2 sv = *(const float2*)&sc[base + 2 * lane];
        sx[nl][2 * lane]     = silu_f(sv.x + a0);
        sx[nl][2 * lane + 1] = silu_f(sv.y + a1);
        if (lane < 8) {
            float2 sw = *(const float2*)&sc[base + 128 + 2 * lane];
            sx[nl][128 + 2 * lane] = silu_f(sw.x + b0);
            sx[nl][129 + 2 * lane] = silu_f(sw.y + b1);
        }
    }
    if (threadIdx.x < 8 * ATTR)
        sat[threadIdx.x >> 2][threadIdx.x & 3] = attr[(size_t)n0 * ATTR + threadIdx.x];
    __syncthreads();

    const int o = threadIdx.x;
    if (o < DOUT) {
        float at[8][ATTR];
        #pragma unroll
        for (int n = 0; n < 8; n++) {
            at[n][0] = sat[n][0]; at[n][1] = sat[n][1];
            at[n][2] = sat[n][2]; at[n][3] = sat[n][3];
        }
        float accA[8], accS[8];
        #pragma unroll
        for (int n = 0; n < 8; n++) { accA[n] = 0.f; accS[n] = 0.f; }
        for (int i = 0; i < 144; i++) {
            float a  = A[(size_t)i * DOUT + o];
            float w0 = Wsc[(size_t)(i * 4 + 0) * DOUT + o];
            float w1 = Wsc[(size_t)(i * 4 + 1) * DOUT + o];
            float w2 = Wsc[(size_t)(i * 4 + 2) * DOUT + o];
            float w3 = Wsc[(size_t)(i * 4 + 3) * DOUT + o];
            #pragma unroll
            for (int n = 0; n < 8; n++) {
                float xi = sx[n][i];
                accA[n] = fmaf(xi, a, accA[n]);
                float s = fmaf(at[n][3], w3,
                          fmaf(at[n][2], w2,
                          fmaf(at[n][1], w1, at[n][0] * w0)));
                accS[n] = fmaf(xi, s, accS[n]);
            }
        }
        #pragma unroll
        for (int n = 0; n < 8; n++) {
            xa  [(size_t)(n0 + n) * DOUT + o] = accA[n];
            aggo[(size_t)(n0 + n) * DOUT + o] = accS[n];
        }
    }
}

// ---------------------------------------------------------------------------
// MFMA edge kernel. R15-exact EXCEPT: src indices read DIRECTLY from global
// per-lane (16-lane broadcast -> L1) instead of via LDS — removes the
// staging->LDS->sidxL round-trip from in front of the xv gather issue, so
// xv latency overlaps embsh staging. posL stays LDS-staged (consumed late
// at copy-out; its latency is already hidden).
// No laundering (R13: exposes L2 latency). No min-waves clause (R2/R8).
// Fragment layouts: A row=lane&15,k=(lane>>4)*8+j ; C/D col=lane&15,row=(lane>>4)*4+reg
// ---------------------------------------------------------------------------
#define T3STEP(T3)                                                             \
    {                                                                          \
        f32x4 shb = mfma16(a_sh, bff[(T3) * 64 + l], Z4);                      \
        f32x4 acc = mfma16(a_h2_0, w3f[((T3) * 4 + 0) * 64 + l], Z4);          \
        acc = mfma16(a_h2_1, w3f[((T3) * 4 + 1) * 64 + l], acc);               \
        acc = mfma16(a_h2_2, w3f[((T3) * 4 + 2) * 64 + l], acc);               \
        acc = mfma16(a_h2_3, w3f[((T3) * 4 + 3) * 64 + l], acc);               \
        const int n = (T3) * 16 + c;                                           \
        float v0 = acc[0] * shb[0] * xv[(T3) * 4 + 0] * INV_SQRT_NB;           \
        float v1 = acc[1] * shb[1] * xv[(T3) * 4 + 1] * INV_SQRT_NB;           \
        float v2 = acc[2] * shb[2] * xv[(T3) * 4 + 2] * INV_SQRT_NB;           \
        float v3 = acc[3] * shb[3] * xv[(T3) * 4 + 3] * INV_SQRT_NB;           \
        int m0 = g * 4;                                                        \
        int d0 = ((m0 + 0) * 96 + (n >> 1)) ^ (((m0 + 0) & 7) << 2);           \
        int d1 = ((m0 + 1) * 96 + (n >> 1)) ^ (((m0 + 1) & 7) << 2);           \
        int d2 = ((m0 + 2) * 96 + (n >> 1)) ^ (((m0 + 2) & 7) << 2);           \
        int d3 = ((m0 + 3) * 96 + (n >> 1)) ^ (((m0 + 3) & 7) << 2);           \
        ((u16*)(h2dw + d0))[n & 1] = f2bf(v0);                                 \
        ((u16*)(h2dw + d1))[n & 1] = f2bf(v1);                                 \
        ((u16*)(h2dw + d2))[n & 1] = f2bf(v2);                                 \
        ((u16*)(h2dw + d3))[n & 1] = f2bf(v3);                                 \
    }

template<int DO, int PK>
__global__ void __launch_bounds__(256)
edge_mfma(const float* __restrict__ emb, const float* __restrict__ sh,
          const u16* __restrict__ embsh,
          const int* __restrict__ src, const int* __restrict__ pos,
          const u16* __restrict__ W1f, const u16* __restrict__ W2f,
          const u16* __restrict__ W3f, const u16* __restrict__ Bf,
          const float* __restrict__ xa, u32* __restrict__ msgdw,
          float* __restrict__ msg3)
{
    __shared__ u32 ldsa[4 * 2400];        // 9600 B per wave, 38400 B/block
    const int wid = threadIdx.x >> 6;
    const int l   = threadIdx.x & 63;
    u32* Wl = ldsa + wid * 2400;
    float* embL  = (float*)Wl;            // PK=0: [16][10] f32 (dw 0..159)
    float* shL   = (float*)(Wl + 160);    // PK=0: [16][9]  f32 (dw 160..303)
    // PK=1: dw 0..159 hold [16][20] bf16 rows (u16)
    int*   posL  = (int*)(Wl + 320);      // [16]
    u32*   h1dw  = Wl + 352;              // [16][32] dw = bf16 [16][64]
    u32*   h2dw  = Wl + 864;              // [16][64] dw h2, reused as [16][96] dw msg

    const bfrag8* w1f = (const bfrag8*)W1f;
    const bfrag8* w2f = (const bfrag8*)W2f;
    const bfrag8* w3f = (const bfrag8*)W3f;
    const bfrag8* bff = (const bfrag8*)Bf;

    const int g = l >> 4, c = l & 15;
    const int gwave = blockIdx.x * 4 + wid;
    const int nwave = gridDim.x * 4;
    const f32x4 Z4 = {0.f, 0.f, 0.f, 0.f};

    for (int it = gwave; it < NE / 16; it += nwave) {
        const int e0 = it * 16;
        // ---- src indices: DIRECT global reads (L1 broadcast), xv issues now ----
        const int si0 = src[e0 + g * 4 + 0], si1 = src[e0 + g * 4 + 1];
        const int si2 = src[e0 + g * 4 + 2], si3 = src[e0 + g * 4 + 3];
        float xv[(DO == 144) ? 36 : 1];
        if constexpr (DO == 144) {
            const float* xr0 = xa + (size_t)si0 * 144;
            const float* xr1 = xa + (size_t)si1 * 144;
            const float* xr2 = xa + (size_t)si2 * 144;
            const float* xr3 = xa + (size_t)si3 * 144;
            #pragma unroll
            for (int t3 = 0; t3 < 9; t3++) {
                xv[t3 * 4 + 0] = xr0[t3 * 16 + c];
                xv[t3 * 4 + 1] = xr1[t3 * 16 + c];
                xv[t3 * 4 + 2] = xr2[t3 * 16 + c];
                xv[t3 * 4 + 3] = xr3[t3 * 16 + c];
            }
        }
        // ---- stage edge data (direct global->LDS); pos staged for copy-out ----
        if constexpr (PK) {
            const u32* ep = (const u32*)embsh + (size_t)e0 * 10;   // 16*20 u16 = 160 dw
            for (int idx = l; idx < 160; idx += 64) Wl[idx] = ep[idx];
            if (l < 16) posL[l] = pos[e0 + l];
        } else {
            const float* ep = emb + (size_t)e0 * NB;
            for (int idx = l; idx < 16 * NB; idx += 64) embL[idx] = ep[idx];
            const float* sp = sh + (size_t)e0 * DSH;
            for (int idx = l; idx < 16 * DSH; idx += 64) shL[idx] = sp[idx];
            if (l < 16) posL[l] = pos[e0 + l];
        }
        // ---- A-frags of emb and sh ----
        bfrag8 a_emb, a_sh;
        {
            const int kb = g << 3;
            if constexpr (PK) {
                const u16* rowp = (const u16*)Wl + c * 20;
                #pragma unroll
                for (int j = 0; j < 8; j++) {
                    int k = kb + j;
                    a_emb[j] = (short)((k < NB)  ? rowp[k]      : (u16)0);
                    a_sh[j]  = (short)((k < DSH) ? rowp[NB + k] : (u16)0);
                }
            } else {
                #pragma unroll
                for (int j = 0; j < 8; j++) {
                    int k = kb + j;
                    a_emb[j] = (short)((k < NB)  ? f2bf(embL[c * NB + k])  : (u16)0);
                    a_sh[j]  = (short)((k < DSH) ? f2bf(shL[c * DSH + k]) : (u16)0);
                }
            }
        }
        // ---- phase A: h1 = silu(emb @ W1), 4 MFMA -> LDS ----
        #pragma unroll
        for (int t = 0; t < 4; t++) {
            f32x4 acc = mfma16(a_emb, w1f[t * 64 + l], Z4);
            #pragma unroll
            for (int r = 0; r < 4; r++) {
                int m = g * 4 + r, n = t * 16 + c;
                int dw = (m * 32 + (n >> 1)) ^ ((m & 7) << 2);
                ((u16*)(h1dw + dw))[n & 1] = f2bf(silu_f(acc[r]));
            }
        }
        bfrag8 a_h1_0, a_h1_1;
        {
            int bb = c * 32 + g * 4, xr = (c & 7) << 2;
            a_h1_0 = *(const bfrag8*)(h1dw + ((bb +  0) ^ xr));
            a_h1_1 = *(const bfrag8*)(h1dw + ((bb + 16) ^ xr));
        }
        // ---- phase B: h2 = silu(h1 @ W2), 16 MFMA -> LDS ----
        #pragma unroll
        for (int t2 = 0; t2 < 8; t2++) {
            f32x4 acc = mfma16(a_h1_0, w2f[(t2 * 2 + 0) * 64 + l], Z4);
            acc = mfma16(a_h1_1, w2f[(t2 * 2 + 1) * 64 + l], acc);
            #pragma unroll
            for (int r = 0; r < 4; r++) {
                int m = g * 4 + r, n = t2 * 16 + c;
                int dw = (m * 64 + (n >> 1)) ^ ((m & 7) << 2);
                ((u16*)(h2dw + dw))[n & 1] = f2bf(silu_f(acc[r]));
            }
        }
        bfrag8 a_h2_0, a_h2_1, a_h2_2, a_h2_3;
        {
            int bb = c * 64 + g * 4, xr = (c & 7) << 2;
            a_h2_0 = *(const bfrag8*)(h2dw + ((bb +  0) ^ xr));
            a_h2_1 = *(const bfrag8*)(h2dw + ((bb + 16) ^ xr));
            a_h2_2 = *(const bfrag8*)(h2dw + ((bb + 32) ^ xr));
            a_h2_3 = *(const bfrag8*)(h2dw + ((bb + 48) ^ xr));
        }

        if constexpr (DO == 144) {
            // ---- phases C+D: 9 static steps; barriers after 2 and 5 ----
            T3STEP(0) T3STEP(1) T3STEP(2)
            __builtin_amdgcn_sched_barrier(0);
            T3STEP(3) T3STEP(4) T3STEP(5)
            __builtin_amdgcn_sched_barrier(0);
            T3STEP(6) T3STEP(7) T3STEP(8)
            // ---- coalesced copy-out, slot-ordered rows ----
            for (int i = l; i < 1152; i += 64) {
                int m = i / 72;
                int xq = i - m * 72;
                u32 v = h2dw[(m * 96 + xq) ^ ((m & 7) << 2)];
                msgdw[(size_t)posL[m] * 72 + xq] = v;
            }
        } else {
            // ---- DO==3: single padded N-tile, direct f32 stores ----
            const int p0 = posL[g * 4 + 0], p1 = posL[g * 4 + 1];
            const int p2 = posL[g * 4 + 2], p3 = posL[g * 4 + 3];
            f32x4 shb = mfma16(a_sh, bff[l], Z4);
            f32x4 acc = mfma16(a_h2_0, w3f[0 * 64 + l], Z4);
            acc = mfma16(a_h2_1, w3f[1 * 64 + l], acc);
            acc = mfma16(a_h2_2, w3f[2 * 64 + l], acc);
            acc = mfma16(a_h2_3, w3f[3 * 64 + l], acc);
            if (c < 3) {
                msg3[(size_t)p0 * 3 + c] = acc[0] * shb[0] * xa[(size_t)si0 * 3 + c] * INV_SQRT_NB;
                msg3[(size_t)p1 * 3 + c] = acc[1] * shb[1] * xa[(size_t)si1 * 3 + c] * INV_SQRT_NB;
                msg3[(size_t)p2 * 3 + c] = acc[2] * shb[2] * xa[(size_t)si2 * 3 + c] * INV_SQRT_NB;
                msg3[(size_t)p3 * 3 + c] = acc[3] * shb[3] * xa[(size_t)si3 * 3 + c] * INV_SQRT_NB;
            }
        }
    }
}

__global__ void gather3(const float* __restrict__ msg3,
                        const int* __restrict__ ptr,
                        float* __restrict__ outb)
{
    int t = blockIdx.x * blockDim.x + threadIdx.x;
    if (t >= NN * 3) return;
    int n = t / 3, o = t - 3 * n;
    float a = 0.f;
    for (int s = ptr[n]; s < ptr[n + 1]; s++) a += msg3[(size_t)s * 3 + o];
    outb[t] += a;   // self-connection already written by gnp<3>
}

// ---------------------------------------------------------------------------
extern "C" void kernel_launch(void* const* d_in, const int* in_sizes, int n_in,
                              void* d_out, int out_size, void* d_ws, size_t ws_size,
                              hipStream_t stream) {
    const float* x    = (const float*)d_in[0];
    const float* attr = (const float*)d_in[1];
    const float* sh   = (const float*)d_in[2];
    const float* emb  = (const float*)d_in[3];
    const float* A0   = (const float*)d_in[4];
    const float* B0   = (const float*)d_in[5];
    const float* W1_0 = (const float*)d_in[6];
    const float* W2_0 = (const float*)d_in[7];
    const float* W3_0 = (const float*)d_in[8];
    const float* Wsc0 = (const float*)d_in[9];
    const float* A1   = (const float*)d_in[10];
    const float* B1   = (const float*)d_in[11];
    const float* W1_1 = (const float*)d_in[12];
    const float* W2_1 = (const float*)d_in[13];
    const float* W3_1 = (const float*)d_in[14];
    const float* Wsc1 = (const float*)d_in[15];
    const float* A2   = (const float*)d_in[16];
    const float* B2   = (const float*)d_in[17];
    const float* W1_2 = (const float*)d_in[18];
    const float* W2_2 = (const float*)d_in[19];
    const float* W3_2 = (const float*)d_in[20];
    const float* Wsc2 = (const float*)d_in[21];
    const int*   src  = (const int*)d_in[22];
    const int*   dst  = (const int*)d_in[23];
    float* out = (float*)d_out;

    // ---- carve workspace ----
    char* wp = (char*)d_ws;
    auto alloc = [&](size_t bytes) -> void* {
        void* r = (void*)wp;
        wp += (bytes + 255) & ~(size_t)255;
        return r;
    };
    float* xa   = (float*)alloc((size_t)NN * 144 * 4);
    float* agg  = (float*)alloc((size_t)NN * 144 * 4);
    float* hb   = (float*)alloc((size_t)NN * 144 * 4);   // layer-1 self-conn
    int*   cnt2 = (int*)alloc((size_t)2 * NN * 4);       // cntD | cntS
    int*   cnt  = cnt2;
    int*   cntS = cnt2 + NN;
    int*   ptr  = (int*)alloc((size_t)(NN + 1) * 4);
    int*   pos  = (int*)alloc((size_t)NE * 4);
    u16* w1f0 = (u16*)alloc(4 * 64 * 8 * 2);
    u16* w2f0 = (u16*)alloc(16 * 64 * 8 * 2);
    u16* w3f0 = (u16*)alloc(36 * 64 * 8 * 2);
    u16* bf0  = (u16*)alloc(9 * 64 * 8 * 2);
    u16* w1f1 = (u16*)alloc(4 * 64 * 8 * 2);
    u16* w2f1 = (u16*)alloc(16 * 64 * 8 * 2);
    u16* w3f1 = (u16*)alloc(36 * 64 * 8 * 2);
    u16* bf1  = (u16*)alloc(9 * 64 * 8 * 2);
    u16* w1f2 = (u16*)alloc(4 * 64 * 8 * 2);
    u16* w2f2 = (u16*)alloc(16 * 64 * 8 * 2);
    u16* w3f2 = (u16*)alloc(4 * 64 * 8 * 2);
    u16* bf2  = (u16*)alloc(1 * 64 * 8 * 2);
    char* msgbase = (char*)alloc((size_t)NE * 288);      // bf16 [E][144]
    u32*   msgdw = (u32*)msgbase;
    float* msg3  = (float*)msgbase;
    // sorted-tier persistents (+256B pad: direct per-lane reads may touch
    // up to 64 ints past the last group's base — keep in-bounds)
    u16* embshS = (u16*)alloc((size_t)NE * 20 * 2 + 256);
    int* srcS   = (int*)alloc((size_t)NE * 4 + 256);
    int* posD2  = (int*)alloc((size_t)NE * 4 + 256);
    size_t sort_need = (size_t)(wp - (char*)d_ws);
    const bool sorted = (ws_size >= sort_need);
    // CSR-S transients live inside msg (dead before edge kernels run)
    int* ordS = (int*)msgbase;                           // [NE]
    int* ptrS = (int*)(msgbase + (size_t)NE * 4 + 256);  // [NN+1]

    if (sorted) {
        hipMemsetAsync(cnt2, 0, (size_t)2 * NN * 4, stream);
        count2_k<<<1024, 256, 0, stream>>>(dst, src, cnt, cntS);
        scan2_k<<<2, 256, 0, stream>>>(cnt, ptr, cntS, ptrS);
        hipMemsetAsync(cnt2, 0, (size_t)2 * NN * 4, stream);
        fill2_k<<<1024, 256, 0, stream>>>(dst, src, ptr, ptrS, cnt, cntS, pos, ordS);
        permute_pack_g<<<(NE + 255) / 256, 256, 0, stream>>>(
            emb, sh, src, pos, ordS, embshS, srcS, posD2);
    } else {
        hipMemsetAsync(cnt, 0, (size_t)NN * 4, stream);
        count_k<<<1024, 256, 0, stream>>>(dst, cnt);
        scan_k<<<1, 256, 0, stream>>>(cnt, ptr);
        hipMemsetAsync(cnt, 0, (size_t)NN * 4, stream);
        fill_k<<<1024, 256, 0, stream>>>(dst, ptr, cnt, pos);
    }

    pack_all<<<39, 256, 0, stream>>>(W1_0, W2_0, W3_0, B0, W1_1, W2_1, W3_1, B1,
                                     W1_2, W2_2, W3_2, B2,
                                     w1f0, w2f0, w3f0, bf0, w1f1, w2f1, w3f1, bf1,
                                     w1f2, w2f2, w3f2, bf2);

    const u16* es = embshS;
    const int* sS = srcS;
    const int* pS = posD2;

    // ---- layer 0 ----
    node_prep<64, 144, 8><<<NN / 8, 192, 0, stream>>>(x, attr, A0, Wsc0, xa, agg);
    if (sorted)
        edge_mfma<144, 1><<<2500, 256, 0, stream>>>(nullptr, nullptr, es, sS, pS,
            w1f0, w2f0, w3f0, bf0, xa, msgdw, nullptr);
    else
        edge_mfma<144, 0><<<2500, 256, 0, stream>>>(emb, sh, nullptr, src, pos,
            w1f0, w2f0, w3f0, bf0, xa, msgdw, nullptr);
    gnp<144><<<NN / 8, 256, 0, stream>>>(msgdw, ptr, agg, attr, A1, Wsc1, xa, hb);

    // ---- layer 1 ----
    if (sorted)
        edge_mfma<144, 1><<<2500, 256, 0, stream>>>(nullptr, nullptr, es, sS, pS,
            w1f1, w2f1, w3f1, bf1, xa, msgdw, nullptr);
    else
        edge_mfma<144, 0><<<2500, 256, 0, stream>>>(emb, sh, nullptr, src, pos,
            w1f1, w2f1, w3f1, bf1, xa, msgdw, nullptr);
    gnp<3><<<NN / 8, 256, 0, stream>>>(msgdw, ptr, hb, attr, A2, Wsc2, xa, out);

    // ---- layer 2 ----
    if (sorted)
        edge_mfma<3, 1><<<2500, 256, 0, stream>>>(nullptr, nullptr, es, sS, pS,
            w1f2, w2f2, w3f2, bf2, xa, nullptr, msg3);
    else
        edge_mfma<3, 0><<<2500, 256, 0, stream>>>(emb, sh, nullptr, src, pos,
            w1f2, w2f2, w3f2, bf2, xa, nullptr, msg3);
    gather3<<<(NN * 3 + 255) / 256, 256, 0, stream>>>(msg3, ptr, out);
}

// Round 17
// 1109.915 us; speedup vs baseline: 1.0172x; 1.0172x over previous
//
#include <hip/hip_runtime.h>
#include <hip/hip_bf16.h>

#define NN 20000
#define NE 640000
#define DSH 9
#define NB 10
#define ATTR 4

typedef __attribute__((ext_vector_type(8))) short bfrag8;  // 8 bf16 (4 VGPR)
typedef __attribute__((ext_vector_type(4))) float f32x4;
typedef unsigned int u32;
typedef unsigned short u16;

constexpr float INV_SQRT_NB = 0.17677669529663687f; // 1/sqrt(32)

// silu via fast rcp (proven R8-R15): rel err 2^-22 << bf16 rounding
__device__ __forceinline__ float silu_f(float x) {
    return x * __builtin_amdgcn_rcpf(1.0f + __expf(-x));
}

__device__ __forceinline__ u16 f2bf(float v) {
    union { __hip_bfloat16 h; u16 u; } c;
    c.h = __float2bfloat16(v);
    return c.u;
}

__device__ __forceinline__ f32x4 mfma16(bfrag8 a, bfrag8 b, f32x4 c) {
    return __builtin_amdgcn_mfma_f32_16x16x32_bf16(a, b, c, 0, 0, 0);
}

// ---------------------------------------------------------------------------
// CSR builds (R14-exact). Fused dual-pass for the sorted tier; fill2 emits
// ordS[slot]=edge so the permute pass is slot-major with coalesced writes.
// ---------------------------------------------------------------------------
__global__ void count_k(const int* __restrict__ idx, int* __restrict__ cnt) {
    int i = blockIdx.x * blockDim.x + threadIdx.x;
    int st = gridDim.x * blockDim.x;
    for (; i < NE; i += st) atomicAdd(&cnt[idx[i]], 1);
}

__global__ void count2_k(const int* __restrict__ dst, const int* __restrict__ src,
                         int* __restrict__ cntD, int* __restrict__ cntS) {
    int i = blockIdx.x * blockDim.x + threadIdx.x;
    int st = gridDim.x * blockDim.x;
    for (; i < NE; i += st) {
        atomicAdd(&cntD[dst[i]], 1);
        atomicAdd(&cntS[src[i]], 1);
    }
}

__device__ __forceinline__ void scan_body(const int* __restrict__ cnt, int* __restrict__ ptr) {
    __shared__ int ssum[256];
    const int T = 256, t = threadIdx.x;
    const int strip = (NN + T - 1) / T;
    int base = t * strip, s = 0;
    for (int i = 0; i < strip; i++) { int idx = base + i; if (idx < NN) s += cnt[idx]; }
    ssum[t] = s; __syncthreads();
    for (int off = 1; off < T; off <<= 1) {
        int v = (t >= off) ? ssum[t - off] : 0;
        __syncthreads();
        ssum[t] += v;
        __syncthreads();
    }
    int run = (t == 0) ? 0 : ssum[t - 1];
    for (int i = 0; i < strip; i++) {
        int idx = base + i;
        if (idx < NN) { int c = cnt[idx]; ptr[idx] = run; run += c; }
    }
    if (t == T - 1) ptr[NN] = run;
}

__global__ void scan_k(const int* __restrict__ cnt, int* __restrict__ ptr) {
    scan_body(cnt, ptr);
}

__global__ void scan2_k(const int* __restrict__ cntD, int* __restrict__ ptrD,
                        const int* __restrict__ cntS, int* __restrict__ ptrS) {
    if (blockIdx.x == 0) scan_body(cntD, ptrD);
    else                 scan_body(cntS, ptrS);
}

__global__ void fill_k(const int* __restrict__ idx, const int* __restrict__ ptr,
                       int* __restrict__ cnt, int* __restrict__ pos) {
    int i = blockIdx.x * blockDim.x + threadIdx.x;
    int st = gridDim.x * blockDim.x;
    for (; i < NE; i += st) {
        int d = idx[i];
        int r = atomicAdd(&cnt[d], 1);
        pos[i] = ptr[d] + r;
    }
}

__global__ void fill2_k(const int* __restrict__ dst, const int* __restrict__ src,
                        const int* __restrict__ ptrD, const int* __restrict__ ptrS,
                        int* __restrict__ cntD, int* __restrict__ cntS,
                        int* __restrict__ pos, int* __restrict__ ordS) {
    int i = blockIdx.x * blockDim.x + threadIdx.x;
    int st = gridDim.x * blockDim.x;
    for (; i < NE; i += st) {
        int d = dst[i];
        pos[i] = ptrD[d] + atomicAdd(&cntD[d], 1);
        int s = src[i];
        ordS[ptrS[s] + atomicAdd(&cntS[s], 1)] = i;
    }
}

// ---------------------------------------------------------------------------
// Slot-major edge materialization (R14-exact): random 40B reads, coalesced
// writes of packed bf16 rows [E][20] (0..9 emb, 10..18 sh, 19 pad).
// ---------------------------------------------------------------------------
__global__ void permute_pack_g(const float* __restrict__ emb, const float* __restrict__ sh,
                               const int* __restrict__ src, const int* __restrict__ pos,
                               const int* __restrict__ ordS,
                               u16* __restrict__ embsh, int* __restrict__ srcS,
                               int* __restrict__ posD2)
{
    int s = blockIdx.x * blockDim.x + threadIdx.x;
    if (s >= NE) return;
    int e = ordS[s];
    u16* row = embsh + (size_t)s * 20;
    #pragma unroll
    for (int k = 0; k < NB; k++)  row[k]      = f2bf(emb[(size_t)e * NB + k]);
    #pragma unroll
    for (int k = 0; k < DSH; k++) row[NB + k] = f2bf(sh[(size_t)e * DSH + k]);
    row[19] = 0;
    srcS[s]  = src[e];
    posD2[s] = pos[e];
}

// ---------------------------------------------------------------------------
// Fused weight packing (R14-exact): all 12 tensors in one launch.
// ---------------------------------------------------------------------------
__global__ void pack_all(const float* __restrict__ W1_0, const float* __restrict__ W2_0,
                         const float* __restrict__ W3_0, const float* __restrict__ B0,
                         const float* __restrict__ W1_1, const float* __restrict__ W2_1,
                         const float* __restrict__ W3_1, const float* __restrict__ B1,
                         const float* __restrict__ W1_2, const float* __restrict__ W2_2,
                         const float* __restrict__ W3_2, const float* __restrict__ B2,
                         u16* __restrict__ w1f0, u16* __restrict__ w2f0,
                         u16* __restrict__ w3f0, u16* __restrict__ bf0,
                         u16* __restrict__ w1f1, u16* __restrict__ w2f1,
                         u16* __restrict__ w3f1, u16* __restrict__ bf1,
                         u16* __restrict__ w1f2, u16* __restrict__ w2f2,
                         u16* __restrict__ w3f2, u16* __restrict__ bf2)
{
    int tid = blockIdx.x * blockDim.x + threadIdx.x;
    int grp = tid >> 6, l = tid & 63;
    if (grp >= 155) return;
    const float* W; u16* out; int K, N, KS, local;
    if      (grp <   4) { W = W1_0; out = w1f0; K = 10;  N = 64;  KS = 1; local = grp;       }
    else if (grp <  20) { W = W2_0; out = w2f0; K = 64;  N = 128; KS = 2; local = grp - 4;   }
    else if (grp <  56) { W = W3_0; out = w3f0; K = 128; N = 144; KS = 4; local = grp - 20;  }
    else if (grp <  65) { W = B0;   out = bf0;  K = 9;   N = 144; KS = 1; local = grp - 56;  }
    else if (grp <  69) { W = W1_1; out = w1f1; K = 10;  N = 64;  KS = 1; local = grp - 65;  }
    else if (grp <  85) { W = W2_1; out = w2f1; K = 64;  N = 128; KS = 2; local = grp - 69;  }
    else if (grp < 121) { W = W3_1; out = w3f1; K = 128; N = 144; KS = 4; local = grp - 85;  }
    else if (grp < 130) { W = B1;   out = bf1;  K = 9;   N = 144; KS = 1; local = grp - 121; }
    else if (grp < 134) { W = W1_2; out = w1f2; K = 10;  N = 64;  KS = 1; local = grp - 130; }
    else if (grp < 150) { W = W2_2; out = w2f2; K = 64;  N = 128; KS = 2; local = grp - 134; }
    else if (grp < 154) { W = W3_2; out = w3f2; K = 128; N = 3;   KS = 4; local = grp - 150; }
    else                { W = B2;   out = bf2;  K = 9;   N = 3;   KS = 1; local = grp - 154; }
    int s = local % KS, t = local / KS;
    int kb = s * 32 + ((l >> 4) << 3);
    int n = t * 16 + (l & 15);
    #pragma unroll
    for (int j = 0; j < 8; j++) {
        int k = kb + j;
        float v = (k < K && n < N) ? W[(size_t)k * N + n] : 0.f;
        out[(size_t)(local * 64 + l) * 8 + j] = f2bf(v);
    }
}

// ---------------------------------------------------------------------------
// Per-node prep (layer 0 only): xa = x @ A, agg = outer(x, attr) @ Wsc
// ---------------------------------------------------------------------------
template<int DI, int DO, int NT>
__global__ void node_prep(const float* __restrict__ xin,
                          const float* __restrict__ attr,
                          const float* __restrict__ A,
                          const float* __restrict__ Wsc,
                          float* __restrict__ xa,
                          float* __restrict__ agg)
{
    __shared__ float sx[NT][DI];
    __shared__ float sat[NT][ATTR];
    const int n0 = blockIdx.x * NT;
    for (int idx = threadIdx.x; idx < NT * DI; idx += blockDim.x)
        sx[idx / DI][idx % DI] = xin[(size_t)n0 * DI + idx];
    if (threadIdx.x < NT * ATTR)
        sat[threadIdx.x / ATTR][threadIdx.x % ATTR] = attr[(size_t)n0 * ATTR + threadIdx.x];
    __syncthreads();

    const int o = threadIdx.x;
    if (o < DO) {
        float at[NT][ATTR];
        #pragma unroll
        for (int n = 0; n < NT; n++) {
            at[n][0] = sat[n][0]; at[n][1] = sat[n][1];
            at[n][2] = sat[n][2]; at[n][3] = sat[n][3];
        }
        float accA[NT], accS[NT];
        #pragma unroll
        for (int n = 0; n < NT; n++) { accA[n] = 0.f; accS[n] = 0.f; }
        for (int i = 0; i < DI; i++) {
            float a  = A[(size_t)i * DO + o];
            float w0 = Wsc[(size_t)(i * 4 + 0) * DO + o];
            float w1 = Wsc[(size_t)(i * 4 + 1) * DO + o];
            float w2 = Wsc[(size_t)(i * 4 + 2) * DO + o];
            float w3 = Wsc[(size_t)(i * 4 + 3) * DO + o];
            #pragma unroll
            for (int n = 0; n < NT; n++) {
                float xi = sx[n][i];
                accA[n] = fmaf(xi, a, accA[n]);
                float s = fmaf(at[n][3], w3,
                          fmaf(at[n][2], w2,
                          fmaf(at[n][1], w1, at[n][0] * w0)));
                accS[n] = fmaf(xi, s, accS[n]);
            }
        }
        #pragma unroll
        for (int n = 0; n < NT; n++) {
            xa [(size_t)(n0 + n) * DO + o] = accA[n];
            agg[(size_t)(n0 + n) * DO + o] = accS[n];
        }
    }
}

// ---------------------------------------------------------------------------
// FUSED layer boundary (R15-exact): gather + self-conn + silu -> LDS, then
// next-layer node_prep. No read/write aliasing.
// ---------------------------------------------------------------------------
template<int DOUT>
__global__ void __launch_bounds__(256)
gnp(const u32* __restrict__ msgdw, const int* __restrict__ ptr,
    const float* __restrict__ sc, const float* __restrict__ attr,
    const float* __restrict__ A, const float* __restrict__ Wsc,
    float* __restrict__ xa, float* __restrict__ aggo)
{
    __shared__ float sx[8][144];
    __shared__ float sat[8][ATTR];
    const int n0 = blockIdx.x * 8;
    const int wid = threadIdx.x >> 6, lane = threadIdx.x & 63;

    #pragma unroll
    for (int k = 0; k < 2; k++) {
        const int nl = wid * 2 + k;
        const int n = n0 + nl;
        const int s0 = ptr[n], s1 = ptr[n + 1];
        float a0 = 0.f, a1 = 0.f, b0 = 0.f, b1 = 0.f;
        for (int s = s0; s < s1; s++) {
            u32 u = msgdw[(size_t)s * 72 + lane];
            a0 += __uint_as_float(u << 16);
            a1 += __uint_as_float(u & 0xffff0000u);
            if (lane < 8) {
                u32 v = msgdw[(size_t)s * 72 + 64 + lane];
                b0 += __uint_as_float(v << 16);
                b1 += __uint_as_float(v & 0xffff0000u);
            }
        }
        size_t base = (size_t)n * 144;
        float2 sv = *(const float2*)&sc[base + 2 * lane];
        sx[nl][2 * lane]     = silu_f(sv.x + a0);
        sx[nl][2 * lane + 1] = silu_f(sv.y + a1);
        if (lane < 8) {
            float2 sw = *(const float2*)&sc[base + 128 + 2 * lane];
            sx[nl][128 + 2 * lane] = silu_f(sw.x + b0);
            sx[nl][129 + 2 * lane] = silu_f(sw.y + b1);
        }
    }
    if (threadIdx.x < 8 * ATTR)
        sat[threadIdx.x >> 2][threadIdx.x & 3] = attr[(size_t)n0 * ATTR + threadIdx.x];
    __syncthreads();

    const int o = threadIdx.x;
    if (o < DOUT) {
        float at[8][ATTR];
        #pragma unroll
        for (int n = 0; n < 8; n++) {
            at[n][0] = sat[n][0]; at[n][1] = sat[n][1];
            at[n][2] = sat[n][2]; at[n][3] = sat[n][3];
        }
        float accA[8], accS[8];
        #pragma unroll
        for (int n = 0; n < 8; n++) { accA[n] = 0.f; accS[n] = 0.f; }
        for (int i = 0; i < 144; i++) {
            float a  = A[(size_t)i * DOUT + o];
            float w0 = Wsc[(size_t)(i * 4 + 0) * DOUT + o];
            float w1 = Wsc[(size_t)(i * 4 + 1) * DOUT + o];
            float w2 = Wsc[(size_t)(i * 4 + 2) * DOUT + o];
            float w3 = Wsc[(size_t)(i * 4 + 3) * DOUT + o];
            #pragma unroll
            for (int n = 0; n < 8; n++) {
                float xi = sx[n][i];
                accA[n] = fmaf(xi, a, accA[n]);
                float s = fmaf(at[n][3], w3,
                          fmaf(at[n][2], w2,
                          fmaf(at[n][1], w1, at[n][0] * w0)));
                accS[n] = fmaf(xi, s, accS[n]);
            }
        }
        #pragma unroll
        for (int n = 0; n < 8; n++) {
            xa  [(size_t)(n0 + n) * DOUT + o] = accA[n];
            aggo[(size_t)(n0 + n) * DOUT + o] = accS[n];
        }
    }
}

// ---------------------------------------------------------------------------
// MFMA edge kernel — R15-exact (best measured config: 236us, VGPR 248).
// src/pos staged via LDS (R16 proved direct global src reads cost issue
// slots, 236->246). No laundering (R13: exposes L2 latency). No min-waves
// clause (R2/R8: forced VGPR cap -> spills).
// PK=1: packed bf16 embsh rows (src-sorted). PK=0: f32 fallback.
// Fragment layouts: A row=lane&15,k=(lane>>4)*8+j ; C/D col=lane&15,row=(lane>>4)*4+reg
// ---------------------------------------------------------------------------
#define T3STEP(T3)                                                             \
    {                                                                          \
        f32x4 shb = mfma16(a_sh, bff[(T3) * 64 + l], Z4);                      \
        f32x4 acc = mfma16(a_h2_0, w3f[((T3) * 4 + 0) * 64 + l], Z4);          \
        acc = mfma16(a_h2_1, w3f[((T3) * 4 + 1) * 64 + l], acc);               \
        acc = mfma16(a_h2_2, w3f[((T3) * 4 + 2) * 64 + l], acc);               \
        acc = mfma16(a_h2_3, w3f[((T3) * 4 + 3) * 64 + l], acc);               \
        const int n = (T3) * 16 + c;                                           \
        float v0 = acc[0] * shb[0] * xv[(T3) * 4 + 0] * INV_SQRT_NB;           \
        float v1 = acc[1] * shb[1] * xv[(T3) * 4 + 1] * INV_SQRT_NB;           \
        float v2 = acc[2] * shb[2] * xv[(T3) * 4 + 2] * INV_SQRT_NB;           \
        float v3 = acc[3] * shb[3] * xv[(T3) * 4 + 3] * INV_SQRT_NB;           \
        int m0 = g * 4;                                                        \
        int d0 = ((m0 + 0) * 96 + (n >> 1)) ^ (((m0 + 0) & 7) << 2);           \
        int d1 = ((m0 + 1) * 96 + (n >> 1)) ^ (((m0 + 1) & 7) << 2);           \
        int d2 = ((m0 + 2) * 96 + (n >> 1)) ^ (((m0 + 2) & 7) << 2);           \
        int d3 = ((m0 + 3) * 96 + (n >> 1)) ^ (((m0 + 3) & 7) << 2);           \
        ((u16*)(h2dw + d0))[n & 1] = f2bf(v0);                                 \
        ((u16*)(h2dw + d1))[n & 1] = f2bf(v1);                                 \
        ((u16*)(h2dw + d2))[n & 1] = f2bf(v2);                                 \
        ((u16*)(h2dw + d3))[n & 1] = f2bf(v3);                                 \
    }

template<int DO, int PK>
__global__ void __launch_bounds__(256)
edge_mfma(const float* __restrict__ emb, const float* __restrict__ sh,
          const u16* __restrict__ embsh,
          const int* __restrict__ src, const int* __restrict__ pos,
          const u16* __restrict__ W1f, const u16* __restrict__ W2f,
          const u16* __restrict__ W3f, const u16* __restrict__ Bf,
          const float* __restrict__ xa, u32* __restrict__ msgdw,
          float* __restrict__ msg3)
{
    __shared__ u32 ldsa[4 * 2400];        // 9600 B per wave, 38400 B/block
    const int wid = threadIdx.x >> 6;
    const int l   = threadIdx.x & 63;
    u32* Wl = ldsa + wid * 2400;
    float* embL  = (float*)Wl;            // PK=0: [16][10] f32 (dw 0..159)
    float* shL   = (float*)(Wl + 160);    // PK=0: [16][9]  f32 (dw 160..303)
    // PK=1: dw 0..159 hold [16][20] bf16 rows (u16)
    int*   sidxL = (int*)(Wl + 304);      // [16]
    int*   posL  = (int*)(Wl + 320);      // [16]          (pad to 352)
    u32*   h1dw  = Wl + 352;              // [16][32] dw = bf16 [16][64]
    u32*   h2dw  = Wl + 864;              // [16][64] dw h2, reused as [16][96] dw msg

    const bfrag8* w1f = (const bfrag8*)W1f;
    const bfrag8* w2f = (const bfrag8*)W2f;
    const bfrag8* w3f = (const bfrag8*)W3f;
    const bfrag8* bff = (const bfrag8*)Bf;

    const int g = l >> 4, c = l & 15;
    const int gwave = blockIdx.x * 4 + wid;
    const int nwave = gridDim.x * 4;
    const f32x4 Z4 = {0.f, 0.f, 0.f, 0.f};

    for (int it = gwave; it < NE / 16; it += nwave) {
        const int e0 = it * 16;
        // ---- stage edge data (direct global->LDS) ----
        if constexpr (PK) {
            const u32* ep = (const u32*)embsh + (size_t)e0 * 10;   // 16*20 u16 = 160 dw
            for (int idx = l; idx < 160; idx += 64) Wl[idx] = ep[idx];
            if (l < 16) { sidxL[l] = src[e0 + l]; posL[l] = pos[e0 + l]; }
        } else {
            const float* ep = emb + (size_t)e0 * NB;
            for (int idx = l; idx < 16 * NB; idx += 64) embL[idx] = ep[idx];
            const float* sp = sh + (size_t)e0 * DSH;
            for (int idx = l; idx < 16 * DSH; idx += 64) shL[idx] = sp[idx];
            if (l < 16) { sidxL[l] = src[e0 + l]; posL[l] = pos[e0 + l]; }
        }
        // ---- read src indices; issue ALL xa-gather loads up front ----
        const int si0 = sidxL[g * 4 + 0], si1 = sidxL[g * 4 + 1];
        const int si2 = sidxL[g * 4 + 2], si3 = sidxL[g * 4 + 3];
        float xv[(DO == 144) ? 36 : 1];
        if constexpr (DO == 144) {
            const float* xr0 = xa + (size_t)si0 * 144;
            const float* xr1 = xa + (size_t)si1 * 144;
            const float* xr2 = xa + (size_t)si2 * 144;
            const float* xr3 = xa + (size_t)si3 * 144;
            #pragma unroll
            for (int t3 = 0; t3 < 9; t3++) {
                xv[t3 * 4 + 0] = xr0[t3 * 16 + c];
                xv[t3 * 4 + 1] = xr1[t3 * 16 + c];
                xv[t3 * 4 + 2] = xr2[t3 * 16 + c];
                xv[t3 * 4 + 3] = xr3[t3 * 16 + c];
            }
        }
        // ---- A-frags of emb and sh ----
        bfrag8 a_emb, a_sh;
        {
            const int kb = g << 3;
            if constexpr (PK) {
                const u16* rowp = (const u16*)Wl + c * 20;
                #pragma unroll
                for (int j = 0; j < 8; j++) {
                    int k = kb + j;
                    a_emb[j] = (short)((k < NB)  ? rowp[k]      : (u16)0);
                    a_sh[j]  = (short)((k < DSH) ? rowp[NB + k] : (u16)0);
                }
            } else {
                #pragma unroll
                for (int j = 0; j < 8; j++) {
                    int k = kb + j;
                    a_emb[j] = (short)((k < NB)  ? f2bf(embL[c * NB + k])  : (u16)0);
                    a_sh[j]  = (short)((k < DSH) ? f2bf(shL[c * DSH + k]) : (u16)0);
                }
            }
        }
        // ---- phase A: h1 = silu(emb @ W1), 4 MFMA -> LDS ----
        #pragma unroll
        for (int t = 0; t < 4; t++) {
            f32x4 acc = mfma16(a_emb, w1f[t * 64 + l], Z4);
            #pragma unroll
            for (int r = 0; r < 4; r++) {
                int m = g * 4 + r, n = t * 16 + c;
                int dw = (m * 32 + (n >> 1)) ^ ((m & 7) << 2);
                ((u16*)(h1dw + dw))[n & 1] = f2bf(silu_f(acc[r]));
            }
        }
        bfrag8 a_h1_0, a_h1_1;
        {
            int bb = c * 32 + g * 4, xr = (c & 7) << 2;
            a_h1_0 = *(const bfrag8*)(h1dw + ((bb +  0) ^ xr));
            a_h1_1 = *(const bfrag8*)(h1dw + ((bb + 16) ^ xr));
        }
        // ---- phase B: h2 = silu(h1 @ W2), 16 MFMA -> LDS ----
        #pragma unroll
        for (int t2 = 0; t2 < 8; t2++) {
            f32x4 acc = mfma16(a_h1_0, w2f[(t2 * 2 + 0) * 64 + l], Z4);
            acc = mfma16(a_h1_1, w2f[(t2 * 2 + 1) * 64 + l], acc);
            #pragma unroll
            for (int r = 0; r < 4; r++) {
                int m = g * 4 + r, n = t2 * 16 + c;
                int dw = (m * 64 + (n >> 1)) ^ ((m & 7) << 2);
                ((u16*)(h2dw + dw))[n & 1] = f2bf(silu_f(acc[r]));
            }
        }
        bfrag8 a_h2_0, a_h2_1, a_h2_2, a_h2_3;
        {
            int bb = c * 64 + g * 4, xr = (c & 7) << 2;
            a_h2_0 = *(const bfrag8*)(h2dw + ((bb +  0) ^ xr));
            a_h2_1 = *(const bfrag8*)(h2dw + ((bb + 16) ^ xr));
            a_h2_2 = *(const bfrag8*)(h2dw + ((bb + 32) ^ xr));
            a_h2_3 = *(const bfrag8*)(h2dw + ((bb + 48) ^ xr));
        }

        if constexpr (DO == 144) {
            // ---- phases C+D: 9 static steps; barriers after 2 and 5 ----
            T3STEP(0) T3STEP(1) T3STEP(2)
            __builtin_amdgcn_sched_barrier(0);
            T3STEP(3) T3STEP(4) T3STEP(5)
            __builtin_amdgcn_sched_barrier(0);
            T3STEP(6) T3STEP(7) T3STEP(8)
            // ---- coalesced copy-out, slot-ordered rows ----
            for (int i = l; i < 1152; i += 64) {
                int m = i / 72;
                int xq = i - m * 72;
                u32 v = h2dw[(m * 96 + xq) ^ ((m & 7) << 2)];
                msgdw[(size_t)posL[m] * 72 + xq] = v;
            }
        } else {
            // ---- DO==3: single padded N-tile, direct f32 stores ----
            const int p0 = posL[g * 4 + 0], p1 = posL[g * 4 + 1];
            const int p2 = posL[g * 4 + 2], p3 = posL[g * 4 + 3];
            f32x4 shb = mfma16(a_sh, bff[l], Z4);
            f32x4 acc = mfma16(a_h2_0, w3f[0 * 64 + l], Z4);
            acc = mfma16(a_h2_1, w3f[1 * 64 + l], acc);
            acc = mfma16(a_h2_2, w3f[2 * 64 + l], acc);
            acc = mfma16(a_h2_3, w3f[3 * 64 + l], acc);
            if (c < 3) {
                msg3[(size_t)p0 * 3 + c] = acc[0] * shb[0] * xa[(size_t)si0 * 3 + c] * INV_SQRT_NB;
                msg3[(size_t)p1 * 3 + c] = acc[1] * shb[1] * xa[(size_t)si1 * 3 + c] * INV_SQRT_NB;
                msg3[(size_t)p2 * 3 + c] = acc[2] * shb[2] * xa[(size_t)si2 * 3 + c] * INV_SQRT_NB;
                msg3[(size_t)p3 * 3 + c] = acc[3] * shb[3] * xa[(size_t)si3 * 3 + c] * INV_SQRT_NB;
            }
        }
    }
}

__global__ void gather3(const float* __restrict__ msg3,
                        const int* __restrict__ ptr,
                        float* __restrict__ outb)
{
    int t = blockIdx.x * blockDim.x + threadIdx.x;
    if (t >= NN * 3) return;
    int n = t / 3, o = t - 3 * n;
    float a = 0.f;
    for (int s = ptr[n]; s < ptr[n + 1]; s++) a += msg3[(size_t)s * 3 + o];
    outb[t] += a;   // self-connection already written by gnp<3>
}

// ---------------------------------------------------------------------------
extern "C" void kernel_launch(void* const* d_in, const int* in_sizes, int n_in,
                              void* d_out, int out_size, void* d_ws, size_t ws_size,
                              hipStream_t stream) {
    const float* x    = (const float*)d_in[0];
    const float* attr = (const float*)d_in[1];
    const float* sh   = (const float*)d_in[2];
    const float* emb  = (const float*)d_in[3];
    const float* A0   = (const float*)d_in[4];
    const float* B0   = (const float*)d_in[5];
    const float* W1_0 = (const float*)d_in[6];
    const float* W2_0 = (const float*)d_in[7];
    const float* W3_0 = (const float*)d_in[8];
    const float* Wsc0 = (const float*)d_in[9];
    const float* A1   = (const float*)d_in[10];
    const float* B1   = (const float*)d_in[11];
    const float* W1_1 = (const float*)d_in[12];
    const float* W2_1 = (const float*)d_in[13];
    const float* W3_1 = (const float*)d_in[14];
    const float* Wsc1 = (const float*)d_in[15];
    const float* A2   = (const float*)d_in[16];
    const float* B2   = (const float*)d_in[17];
    const float* W1_2 = (const float*)d_in[18];
    const float* W2_2 = (const float*)d_in[19];
    const float* W3_2 = (const float*)d_in[20];
    const float* Wsc2 = (const float*)d_in[21];
    const int*   src  = (const int*)d_in[22];
    const int*   dst  = (const int*)d_in[23];
    float* out = (float*)d_out;

    // ---- carve workspace ----
    char* wp = (char*)d_ws;
    auto alloc = [&](size_t bytes) -> void* {
        void* r = (void*)wp;
        wp += (bytes + 255) & ~(size_t)255;
        return r;
    };
    float* xa   = (float*)alloc((size_t)NN * 144 * 4);
    float* agg  = (float*)alloc((size_t)NN * 144 * 4);
    float* hb   = (float*)alloc((size_t)NN * 144 * 4);   // layer-1 self-conn
    int*   cnt2 = (int*)alloc((size_t)2 * NN * 4);       // cntD | cntS
    int*   cnt  = cnt2;
    int*   cntS = cnt2 + NN;
    int*   ptr  = (int*)alloc((size_t)(NN + 1) * 4);
    int*   pos  = (int*)alloc((size_t)NE * 4);
    u16* w1f0 = (u16*)alloc(4 * 64 * 8 * 2);
    u16* w2f0 = (u16*)alloc(16 * 64 * 8 * 2);
    u16* w3f0 = (u16*)alloc(36 * 64 * 8 * 2);
    u16* bf0  = (u16*)alloc(9 * 64 * 8 * 2);
    u16* w1f1 = (u16*)alloc(4 * 64 * 8 * 2);
    u16* w2f1 = (u16*)alloc(16 * 64 * 8 * 2);
    u16* w3f1 = (u16*)alloc(36 * 64 * 8 * 2);
    u16* bf1  = (u16*)alloc(9 * 64 * 8 * 2);
    u16* w1f2 = (u16*)alloc(4 * 64 * 8 * 2);
    u16* w2f2 = (u16*)alloc(16 * 64 * 8 * 2);
    u16* w3f2 = (u16*)alloc(4 * 64 * 8 * 2);
    u16* bf2  = (u16*)alloc(1 * 64 * 8 * 2);
    char* msgbase = (char*)alloc((size_t)NE * 288);      // bf16 [E][144]
    u32*   msgdw = (u32*)msgbase;
    float* msg3  = (float*)msgbase;
    // sorted-tier persistents
    u16* embshS = (u16*)alloc((size_t)NE * 20 * 2);
    int* srcS   = (int*)alloc((size_t)NE * 4);
    int* posD2  = (int*)alloc((size_t)NE * 4);
    size_t sort_need = (size_t)(wp - (char*)d_ws);
    const bool sorted = (ws_size >= sort_need);
    // CSR-S transients live inside msg (dead before edge kernels run)
    int* ordS = (int*)msgbase;                           // [NE]
    int* ptrS = (int*)(msgbase + (size_t)NE * 4 + 256);  // [NN+1]

    if (sorted) {
        hipMemsetAsync(cnt2, 0, (size_t)2 * NN * 4, stream);
        count2_k<<<1024, 256, 0, stream>>>(dst, src, cnt, cntS);
        scan2_k<<<2, 256, 0, stream>>>(cnt, ptr, cntS, ptrS);
        hipMemsetAsync(cnt2, 0, (size_t)2 * NN * 4, stream);
        fill2_k<<<1024, 256, 0, stream>>>(dst, src, ptr, ptrS, cnt, cntS, pos, ordS);
        permute_pack_g<<<(NE + 255) / 256, 256, 0, stream>>>(
            emb, sh, src, pos, ordS, embshS, srcS, posD2);
    } else {
        hipMemsetAsync(cnt, 0, (size_t)NN * 4, stream);
        count_k<<<1024, 256, 0, stream>>>(dst, cnt);
        scan_k<<<1, 256, 0, stream>>>(cnt, ptr);
        hipMemsetAsync(cnt, 0, (size_t)NN * 4, stream);
        fill_k<<<1024, 256, 0, stream>>>(dst, ptr, cnt, pos);
    }

    pack_all<<<39, 256, 0, stream>>>(W1_0, W2_0, W3_0, B0, W1_1, W2_1, W3_1, B1,
                                     W1_2, W2_2, W3_2, B2,
                                     w1f0, w2f0, w3f0, bf0, w1f1, w2f1, w3f1, bf1,
                                     w1f2, w2f2, w3f2, bf2);

    const u16* es = embshS;
    const int* sS = srcS;
    const int* pS = posD2;

    // ---- layer 0 ----
    node_prep<64, 144, 8><<<NN / 8, 192, 0, stream>>>(x, attr, A0, Wsc0, xa, agg);
    if (sorted)
        edge_mfma<144, 1><<<2500, 256, 0, stream>>>(nullptr, nullptr, es, sS, pS,
            w1f0, w2f0, w3f0, bf0, xa, msgdw, nullptr);
    else
        edge_mfma<144, 0><<<2500, 256, 0, stream>>>(emb, sh, nullptr, src, pos,
            w1f0, w2f0, w3f0, bf0, xa, msgdw, nullptr);
    gnp<144><<<NN / 8, 256, 0, stream>>>(msgdw, ptr, agg, attr, A1, Wsc1, xa, hb);

    // ---- layer 1 ----
    if (sorted)
        edge_mfma<144, 1><<<2500, 256, 0, stream>>>(nullptr, nullptr, es, sS, pS,
            w1f1, w2f1, w3f1, bf1, xa, msgdw, nullptr);
    else
        edge_mfma<144, 0><<<2500, 256, 0, stream>>>(emb, sh, nullptr, src, pos,
            w1f1, w2f1, w3f1, bf1, xa, msgdw, nullptr);
    gnp<3><<<NN / 8, 256, 0, stream>>>(msgdw, ptr, hb, attr, A2, Wsc2, xa, out);

    // ---- layer 2 ----
    if (sorted)
        edge_mfma<3, 1><<<2500, 256, 0, stream>>>(nullptr, nullptr, es, sS, pS,
            w1f2, w2f2, w3f2, bf2, xa, nullptr, msg3);
    else
        edge_mfma<3, 0><<<2500, 256, 0, stream>>>(emb, sh, nullptr, src, pos,
            w1f2, w2f2, w3f2, bf2, xa, nullptr, msg3);
    gather3<<<(NN * 3 + 255) / 256, 256, 0, stream>>>(msg3, ptr, out);
}